// Round 10
// baseline (697.949 us; speedup 1.0000x reference)
//
#include <hip/hip_runtime.h>
#include <hip/hip_fp16.h>

#define N_NODES 100000
#define N_EDGES 1600000
#define N_GRAPHS 512
#define F 128
#define N_CONVS 4
#define SCAN_NBLK ((N_NODES + 1023) / 1024)   // 98
#define FILL_BLOCKS ((N_EDGES + 255) / 256)   // 6250
#define GEMM64_BLOCKS ((N_NODES + 63) / 64)   // 1563
#define FUSE_BLOCKS ((N_NODES + 63) / 64)     // 1563 (64 nodes/block)

// packed W2 row stride: 256 bf16 (hi/lo interleaved) padded to 264 = 132 dwords
#define W2_STRIDE 132
#define W2_LAYER (128 * W2_STRIDE)            // dwords per layer

typedef __attribute__((ext_vector_type(8))) short short8;   // 8 bf16 (4 VGPRs)
typedef __attribute__((ext_vector_type(4))) float f32x4;

union FragU { uint4 u; short8 v; };
union HU { uint2 u; __half2 h[2]; };
union HU4 { uint4 u; __half2 h[4]; };

__device__ __forceinline__ float4 fma4(float w, float4 v, float4 a) {
    a.x = fmaf(w, v.x, a.x); a.y = fmaf(w, v.y, a.y);
    a.z = fmaf(w, v.z, a.z); a.w = fmaf(w, v.w, a.w);
    return a;
}

// float4 -> 4 fp16 (RNE) packed in uint2
__device__ __forceinline__ uint2 f4_to_h4(float4 f) {
    HU x;
    x.h[0] = __floats2half2_rn(f.x, f.y);
    x.h[1] = __floats2half2_rn(f.z, f.w);
    return x.u;
}

// split f into truncated-bf16 hi/lo, packed (hi in low16, lo in high16).
__device__ __forceinline__ unsigned int pack_hilo(float f) {
    unsigned int u = __float_as_uint(f);
    unsigned int hb = u & 0xFFFF0000u;
    float d = f - __uint_as_float(hb);
    unsigned int lb = __float_as_uint(d) >> 16;
    return (u >> 16) | (lb << 16);
}

// ---------------- CSR build ----------------

__global__ void count_kernel(const int* __restrict__ dst, int* __restrict__ cnt) {
    int e = blockIdx.x * blockDim.x + threadIdx.x;
    if (e < N_EDGES) atomicAdd(&cnt[dst[e]], 1);
}

__global__ void dinv_kernel(const int* __restrict__ cnt, float* __restrict__ dinv) {
    int n = blockIdx.x * blockDim.x + threadIdx.x;
    if (n < N_NODES) dinv[n] = rsqrtf((float)cnt[n] + 2.0f);  // improved=True
}

__global__ void scan1_kernel(const int* __restrict__ cnt, int* __restrict__ excl,
                             int* __restrict__ blksum) {
    __shared__ int sums[256];
    int t = threadIdx.x;
    int base = blockIdx.x * 1024 + t * 4;
    int v0 = 0, v1 = 0, v2 = 0, v3 = 0;
    if (base + 0 < N_NODES) v0 = cnt[base + 0];
    if (base + 1 < N_NODES) v1 = cnt[base + 1];
    if (base + 2 < N_NODES) v2 = cnt[base + 2];
    if (base + 3 < N_NODES) v3 = cnt[base + 3];
    int s = v0 + v1 + v2 + v3;
    sums[t] = s;
    __syncthreads();
    for (int off = 1; off < 256; off <<= 1) {
        int y = (t >= off) ? sums[t - off] : 0;
        __syncthreads();
        sums[t] += y;
        __syncthreads();
    }
    int pre = sums[t] - s;
    if (base + 0 < N_NODES) excl[base + 0] = pre;
    if (base + 1 < N_NODES) excl[base + 1] = pre + v0;
    if (base + 2 < N_NODES) excl[base + 2] = pre + v0 + v1;
    if (base + 3 < N_NODES) excl[base + 3] = pre + v0 + v1 + v2;
    if (t == 255) blksum[blockIdx.x] = sums[255];
}

__global__ void scan2_kernel(int* __restrict__ blksum, int nblk) {
    __shared__ int sh[128];
    int t = threadIdx.x;
    int v = (t < nblk) ? blksum[t] : 0;
    sh[t] = v;
    __syncthreads();
    for (int off = 1; off < 128; off <<= 1) {
        int y = (t >= off) ? sh[t - off] : 0;
        __syncthreads();
        sh[t] += y;
        __syncthreads();
    }
    if (t < nblk) blksum[t] = sh[t] - v;
}

__global__ void scan3_kernel(int* __restrict__ rowptr, const int* __restrict__ blksum,
                             int* __restrict__ fill) {
    int t = threadIdx.x;
    int base = blockIdx.x * 1024 + t * 4;
    int off = blksum[blockIdx.x];
#pragma unroll
    for (int i = 0; i < 4; i++) {
        int idx = base + i;
        if (idx < N_NODES) {
            int v = rowptr[idx] + off;
            rowptr[idx] = v;
            fill[idx] = v;
        }
    }
    if (blockIdx.x == 0 && t == 0) rowptr[N_NODES] = N_EDGES;
}

// ---------------- W pre-pack: conv_w[L][k][n] -> W2g[L][n][132 dwords] ----------------

__global__ void wpack_kernel(const float* __restrict__ conv_w, unsigned int* __restrict__ W2g) {
    int idx = blockIdx.x * 256 + threadIdx.x;
    if (idx < N_CONVS * 16384) {
        int L = idx >> 14;
        int e = idx & 16383;
        int k = e >> 7;
        int n = e & 127;
        float f = conv_w[(size_t)L * 16384 + k * 128 + n];
        W2g[(size_t)L * W2_LAYER + n * W2_STRIDE + k] = pack_hilo(f);
    }
}

// ---------------- Fused: CSR fill scatter  ||  GEMM layer 0 (VALU, fp16 out) --------

__global__ __launch_bounds__(256) void fill_gemm0_kernel(
        const int* __restrict__ src, const int* __restrict__ dst,
        const float* __restrict__ dinv, int* __restrict__ fill,
        int2* __restrict__ edges,
        const float* __restrict__ X, const float* __restrict__ W,
        uint2* __restrict__ H2) {
    __shared__ float xs[64 * 128];   // 32 KB (gemm blocks only)
    int t = threadIdx.x;

    if (blockIdx.x < FILL_BLOCKS) {
        int e = blockIdx.x * 256 + t;
        if (e < N_EDGES) {
            int d = dst[e];
            int s = src[e];
            int pos = atomicAdd(&fill[d], 1);
            edges[pos] = make_int2(s, __float_as_int(dinv[s] * dinv[d]));
        }
        return;
    }

    int gb = blockIdx.x - FILL_BLOCKS;
    int row0b = gb * 64;

#pragma unroll
    for (int i = 0; i < 8; i++) {
        int idx = i * 256 + t;
        int r = idx >> 5;
        int c4 = idx & 31;
        int row = row0b + r;
        if (row > N_NODES - 1) row = N_NODES - 1;
        *(float4*)(&xs[r * 128 + c4 * 4]) = *(const float4*)(X + (size_t)row * F + c4 * 4);
    }
    __syncthreads();

    int cg = t & 31;
    int rg = t >> 5;
    const float4* W4 = (const float4*)W;

    float4 acc[8];
#pragma unroll
    for (int i = 0; i < 8; i++) acc[i] = make_float4(0.f, 0.f, 0.f, 0.f);

#pragma unroll 2
    for (int k4 = 0; k4 < 32; k4++) {
        float4 w0 = W4[(k4 * 4 + 0) * 32 + cg];
        float4 w1 = W4[(k4 * 4 + 1) * 32 + cg];
        float4 w2 = W4[(k4 * 4 + 2) * 32 + cg];
        float4 w3 = W4[(k4 * 4 + 3) * 32 + cg];
#pragma unroll
        for (int i = 0; i < 8; i++) {
            float4 xv = *(const float4*)(&xs[(rg * 8 + i) * 128 + k4 * 4]);
            acc[i] = fma4(xv.x, w0, acc[i]);
            acc[i] = fma4(xv.y, w1, acc[i]);
            acc[i] = fma4(xv.z, w2, acc[i]);
            acc[i] = fma4(xv.w, w3, acc[i]);
        }
    }

#pragma unroll
    for (int i = 0; i < 8; i++) {
        int r = row0b + rg * 8 + i;
        if (r < N_NODES) H2[(size_t)r * 32 + cg] = f4_to_h4(acc[i]);
    }
}

// ---------------- Fused agg_L + GEMM_{L+1}: H_next = relu(agg+self+b) @ W ----------
// Block = 256 = 4 waves, 64 nodes. Phase 1: wave w aggs nodes [blk*64+w*16, +16)
// one at a time (lane = slot 0..3 x c16 0..15; uint4 gathers, 16 in flight/wave)
// and packs the relu'd row as split-bf16 dwords into LDS (stride 132 -> 2-way
// bank aliasing only). Phase 2: the verified split-bf16 MFMA over the wave's own
// 16-row tile; B-frags streamed from L2-resident packed W (67 KB); fp16 out.

__global__ __launch_bounds__(256) void aggfuse_kernel(
        const uint4* __restrict__ H16, const int* __restrict__ rowptr,
        const int2* __restrict__ edges, const float* __restrict__ dinv,
        const float4* __restrict__ bias4, const unsigned int* __restrict__ W2g,
        __half* __restrict__ Hh) {
    __shared__ unsigned int alds[64 * W2_STRIDE];   // 33.8 KB
    int t = threadIdx.x;
    int w = t >> 6;
    int lane = t & 63;
    int c16 = lane & 15;
    int slot = lane >> 4;
    int nb0 = blockIdx.x * 64 + w * 16;   // this wave's 16 tile rows (nodes)

    for (int nn = 0; nn < 16; nn++) {
        int node = nb0 + nn;
        int nodec = (node > N_NODES - 1) ? (N_NODES - 1) : node;
        int lo = rowptr[nodec];
        int hi = rowptr[nodec + 1];
        int him1 = hi - 1;

        float4 aL = make_float4(0.f, 0.f, 0.f, 0.f);
        float4 aH = make_float4(0.f, 0.f, 0.f, 0.f);

        for (int i = lo + slot; i < hi; i += 16) {
            int s[4]; float wt[4]; uint4 v[4];
#pragma unroll
            for (int j = 0; j < 4; j++) {
                int ij = i + 4 * j;
                int cj = (ij < him1) ? ij : him1;
                int2 e = edges[cj];
                s[j] = e.x;
                wt[j] = (ij < hi) ? __int_as_float(e.y) : 0.f;
            }
#pragma unroll
            for (int j = 0; j < 4; j++) v[j] = H16[(size_t)s[j] * 16 + c16];
#pragma unroll
            for (int j = 0; j < 4; j++) {
                HU4 x; x.u = v[j];
                float2 p0 = __half22float2(x.h[0]);
                float2 p1 = __half22float2(x.h[1]);
                float2 p2 = __half22float2(x.h[2]);
                float2 p3 = __half22float2(x.h[3]);
                aL.x = fmaf(wt[j], p0.x, aL.x); aL.y = fmaf(wt[j], p0.y, aL.y);
                aL.z = fmaf(wt[j], p1.x, aL.z); aL.w = fmaf(wt[j], p1.y, aL.w);
                aH.x = fmaf(wt[j], p2.x, aH.x); aH.y = fmaf(wt[j], p2.y, aH.y);
                aH.z = fmaf(wt[j], p3.x, aH.z); aH.w = fmaf(wt[j], p3.y, aH.w);
            }
        }

        aL.x += __shfl_down(aL.x, 32, 64); aL.y += __shfl_down(aL.y, 32, 64);
        aL.z += __shfl_down(aL.z, 32, 64); aL.w += __shfl_down(aL.w, 32, 64);
        aH.x += __shfl_down(aH.x, 32, 64); aH.y += __shfl_down(aH.y, 32, 64);
        aH.z += __shfl_down(aH.z, 32, 64); aH.w += __shfl_down(aH.w, 32, 64);
        aL.x += __shfl_down(aL.x, 16, 64); aL.y += __shfl_down(aL.y, 16, 64);
        aL.z += __shfl_down(aL.z, 16, 64); aL.w += __shfl_down(aL.w, 16, 64);
        aH.x += __shfl_down(aH.x, 16, 64); aH.y += __shfl_down(aH.y, 16, 64);
        aH.z += __shfl_down(aH.z, 16, 64); aH.w += __shfl_down(aH.w, 16, 64);

        if (slot == 0) {
            float dn = dinv[nodec];
            float sw = 2.0f * dn * dn;
            HU4 x; x.u = H16[(size_t)nodec * 16 + c16];
            float2 p0 = __half22float2(x.h[0]);
            float2 p1 = __half22float2(x.h[1]);
            float2 p2 = __half22float2(x.h[2]);
            float2 p3 = __half22float2(x.h[3]);
            float4 bL = bias4[c16 * 2];
            float4 bH = bias4[c16 * 2 + 1];
            float rv[8];
            rv[0] = fmaxf(fmaf(sw, p0.x, aL.x) + bL.x, 0.f);
            rv[1] = fmaxf(fmaf(sw, p0.y, aL.y) + bL.y, 0.f);
            rv[2] = fmaxf(fmaf(sw, p1.x, aL.z) + bL.z, 0.f);
            rv[3] = fmaxf(fmaf(sw, p1.y, aL.w) + bL.w, 0.f);
            rv[4] = fmaxf(fmaf(sw, p2.x, aH.x) + bH.x, 0.f);
            rv[5] = fmaxf(fmaf(sw, p2.y, aH.y) + bH.y, 0.f);
            rv[6] = fmaxf(fmaf(sw, p3.x, aH.z) + bH.z, 0.f);
            rv[7] = fmaxf(fmaf(sw, p3.y, aH.w) + bH.w, 0.f);
            int base = (w * 16 + nn) * W2_STRIDE + c16 * 8;
#pragma unroll
            for (int j = 0; j < 8; j++) alds[base + j] = pack_hilo(rv[j]);
        }
    }
    __syncthreads();

    // Phase 2: split-bf16 MFMA, A = wave's own LDS tile, B from global (L2-hot)
    int m = c16, q = slot;
    uint4 afr[8];
#pragma unroll
    for (int i = 0; i < 8; i++)
        afr[i] = *(const uint4*)&alds[(w * 16 + m) * W2_STRIDE + (i * 4 + q) * 4];

    f32x4 acc[8];
#pragma unroll
    for (int nb = 0; nb < 8; nb++) acc[nb] = (f32x4){0.f, 0.f, 0.f, 0.f};

#pragma unroll
    for (int nb = 0; nb < 8; nb++) {
        const unsigned int* wb = W2g + (size_t)(nb * 16 + m) * W2_STRIDE;
#pragma unroll
        for (int i = 0; i < 8; i++) {
            uint4 b = *(const uint4*)(wb + i * 16 + q * 4);
            FragU fa, fb, fr;
            fa.u = afr[i];
            fb.u = b;
            acc[nb] = __builtin_amdgcn_mfma_f32_16x16x32_bf16(fa.v, fb.v, acc[nb], 0, 0, 0);
            fr.u.x = (b.x >> 16) | (b.x << 16);
            fr.u.y = (b.y >> 16) | (b.y << 16);
            fr.u.z = (b.z >> 16) | (b.z << 16);
            fr.u.w = (b.w >> 16) | (b.w << 16);
            acc[nb] = __builtin_amdgcn_mfma_f32_16x16x32_bf16(fa.v, fr.v, acc[nb], 0, 0, 0);
        }
    }

    int rbase = nb0 + q * 4;   // C/D: col = m, row = q*4 + r within tile
#pragma unroll
    for (int nb = 0; nb < 8; nb++) {
#pragma unroll
        for (int r = 0; r < 4; r++) {
            int row = rbase + r;
            if (row < N_NODES) Hh[(size_t)row * F + nb * 16 + m] = __float2half(acc[nb][r]);
        }
    }
}

// ---------------- Plain aggregation (final layer): fp32 out for pooling ----------

__global__ __launch_bounds__(256) void agg_kernel(const uint4* __restrict__ H16,
                                                  const int* __restrict__ rowptr,
                                                  const int2* __restrict__ edges,
                                                  const float* __restrict__ dinv,
                                                  const float4* __restrict__ bias4,
                                                  float4* __restrict__ Xo4) {
    int node = blockIdx.x * 4 + (threadIdx.x >> 6);
    if (node >= N_NODES) return;
    int lane = threadIdx.x & 63;
    int c16 = lane & 15;
    int slot = lane >> 4;

    int lo = rowptr[node];
    int hi = rowptr[node + 1];
    int him1 = hi - 1;

    float4 aL = make_float4(0.f, 0.f, 0.f, 0.f);
    float4 aH = make_float4(0.f, 0.f, 0.f, 0.f);

    for (int i = lo + slot; i < hi; i += 16) {
        int s[4]; float w[4]; uint4 v[4];
#pragma unroll
        for (int j = 0; j < 4; j++) {
            int ij = i + 4 * j;
            int cj = (ij < him1) ? ij : him1;
            int2 e = edges[cj];
            s[j] = e.x;
            w[j] = (ij < hi) ? __int_as_float(e.y) : 0.f;
        }
#pragma unroll
        for (int j = 0; j < 4; j++) v[j] = H16[(size_t)s[j] * 16 + c16];
#pragma unroll
        for (int j = 0; j < 4; j++) {
            HU4 x; x.u = v[j];
            float2 p0 = __half22float2(x.h[0]);
            float2 p1 = __half22float2(x.h[1]);
            float2 p2 = __half22float2(x.h[2]);
            float2 p3 = __half22float2(x.h[3]);
            aL.x = fmaf(w[j], p0.x, aL.x); aL.y = fmaf(w[j], p0.y, aL.y);
            aL.z = fmaf(w[j], p1.x, aL.z); aL.w = fmaf(w[j], p1.y, aL.w);
            aH.x = fmaf(w[j], p2.x, aH.x); aH.y = fmaf(w[j], p2.y, aH.y);
            aH.z = fmaf(w[j], p3.x, aH.z); aH.w = fmaf(w[j], p3.y, aH.w);
        }
    }

    aL.x += __shfl_down(aL.x, 32, 64); aL.y += __shfl_down(aL.y, 32, 64);
    aL.z += __shfl_down(aL.z, 32, 64); aL.w += __shfl_down(aL.w, 32, 64);
    aH.x += __shfl_down(aH.x, 32, 64); aH.y += __shfl_down(aH.y, 32, 64);
    aH.z += __shfl_down(aH.z, 32, 64); aH.w += __shfl_down(aH.w, 32, 64);
    aL.x += __shfl_down(aL.x, 16, 64); aL.y += __shfl_down(aL.y, 16, 64);
    aL.z += __shfl_down(aL.z, 16, 64); aL.w += __shfl_down(aL.w, 16, 64);
    aH.x += __shfl_down(aH.x, 16, 64); aH.y += __shfl_down(aH.y, 16, 64);
    aH.z += __shfl_down(aH.z, 16, 64); aH.w += __shfl_down(aH.w, 16, 64);

    if (slot == 0) {
        float dn = dinv[node];
        float sw = 2.0f * dn * dn;
        HU4 x; x.u = H16[(size_t)node * 16 + c16];
        float2 p0 = __half22float2(x.h[0]);
        float2 p1 = __half22float2(x.h[1]);
        float2 p2 = __half22float2(x.h[2]);
        float2 p3 = __half22float2(x.h[3]);
        float4 bL = bias4[c16 * 2];
        float4 bH = bias4[c16 * 2 + 1];
        float4 rL, rH;
        rL.x = fmaxf(fmaf(sw, p0.x, aL.x) + bL.x, 0.f);
        rL.y = fmaxf(fmaf(sw, p0.y, aL.y) + bL.y, 0.f);
        rL.z = fmaxf(fmaf(sw, p1.x, aL.z) + bL.z, 0.f);
        rL.w = fmaxf(fmaf(sw, p1.y, aL.w) + bL.w, 0.f);
        rH.x = fmaxf(fmaf(sw, p2.x, aH.x) + bH.x, 0.f);
        rH.y = fmaxf(fmaf(sw, p2.y, aH.y) + bH.y, 0.f);
        rH.z = fmaxf(fmaf(sw, p3.x, aH.z) + bH.z, 0.f);
        rH.w = fmaxf(fmaf(sw, p3.y, aH.w) + bH.w, 0.f);
        Xo4[(size_t)node * 32 + c16 * 2]     = rL;
        Xo4[(size_t)node * 32 + c16 * 2 + 1] = rH;
    }
}

// ---------------- Fused mean-pool + FC1(relu) + FC2 ----------------

__global__ __launch_bounds__(256) void pool_fc_kernel(const float* __restrict__ x,
                                                      const int* __restrict__ batch,
                                                      const float* __restrict__ fc1w,
                                                      const float* __restrict__ fc1b,
                                                      const float* __restrict__ fc2w,
                                                      const float* __restrict__ fc2b,
                                                      float* __restrict__ out) {
    __shared__ float part[2][F];
    __shared__ float pooled[F];
    __shared__ int bnd[2];
    __shared__ float red[2];
    int g = blockIdx.x, t = threadIdx.x;
    int c = t & 127, hlf = t >> 7;

    if (t < 2) {
        int target = g + t;
        int lo = 0, hi = N_NODES;
        while (lo < hi) {
            int m = (lo + hi) >> 1;
            if (batch[m] < target) lo = m + 1;
            else hi = m;
        }
        bnd[t] = lo;
    }
    __syncthreads();
    int lo = bnd[0], hi = bnd[1];

    float s = 0.f;
    int n = lo + hlf;
    for (; n + 6 < hi; n += 8) {
        float v0 = x[(size_t)n * F + c];
        float v1 = x[(size_t)(n + 2) * F + c];
        float v2 = x[(size_t)(n + 4) * F + c];
        float v3 = x[(size_t)(n + 6) * F + c];
        s += (v0 + v1) + (v2 + v3);
    }
    for (; n < hi; n += 2) s += x[(size_t)n * F + c];
    part[hlf][c] = s;
    __syncthreads();

    if (t < F) {
        float cntf = fmaxf((float)(hi - lo), 1.0f);
        pooled[c] = (part[0][c] + part[1][c]) / cntf;
    }
    __syncthreads();

    if (t < F) {
        float acc = fc1b[t];
#pragma unroll 4
        for (int k = 0; k < F; k++) acc = fmaf(pooled[k], fc1w[k * F + t], acc);
        acc = fmaxf(acc, 0.f);

        float p = acc * fc2w[t];
#pragma unroll
        for (int o = 32; o > 0; o >>= 1) p += __shfl_down(p, o, 64);
        if ((t & 63) == 0) red[t >> 6] = p;
    }
    __syncthreads();
    if (t == 0) out[g] = red[0] + red[1] + fc2b[0];
}

// ---------------- launch ----------------

extern "C" void kernel_launch(void* const* d_in, const int* in_sizes, int n_in,
                              void* d_out, int out_size, void* d_ws, size_t ws_size,
                              hipStream_t stream) {
    const float* x_in   = (const float*)d_in[0];
    const int*   eidx   = (const int*)d_in[1];
    const int*   batch  = (const int*)d_in[2];
    const float* conv_w = (const float*)d_in[4];
    const float* conv_b = (const float*)d_in[5];
    const float* fc1w   = (const float*)d_in[6];
    const float* fc1b   = (const float*)d_in[7];
    const float* fc2w   = (const float*)d_in[8];
    const float* fc2b   = (const float*)d_in[9];
    float* out = (float*)d_out;

    const int* src = eidx;
    const int* dst = eidx + N_EDGES;

    char* ws = (char*)d_ws;
    size_t off = 0;
    auto alloc = [&](size_t bytes) -> char* {
        char* p = ws + off;
        off += (bytes + 255) & ~(size_t)255;
        return p;
    };
    float*  bufA  = (float*)alloc((size_t)N_NODES * F * 4);    // 51.2 MB fp32 (final agg out)
    __half* bufHa = (__half*)alloc((size_t)N_NODES * F * 2);   // 25.6 MB fp16
    __half* bufHb = (__half*)alloc((size_t)N_NODES * F * 2);   // 25.6 MB fp16
    float*  dinv  = (float*)alloc((size_t)N_NODES * 4);
    int*    cnt   = (int*)alloc((size_t)N_NODES * 4);
    int*    rowp  = (int*)alloc((size_t)(N_NODES + 1) * 4);
    int*    fill  = (int*)alloc((size_t)N_NODES * 4);
    int2*   edges = (int2*)alloc((size_t)N_EDGES * 8);         // 12.8 MB packed
    unsigned int* W2g = (unsigned int*)alloc((size_t)N_CONVS * W2_LAYER * 4);  // 264 KB
    int*    blks  = (int*)alloc(128 * 4);
    (void)ws_size; (void)in_sizes; (void)n_in; (void)out_size;

    // --- CSR prep + W pre-pack ---
    hipMemsetAsync(cnt, 0, (size_t)N_NODES * 4, stream);
    count_kernel<<<(N_EDGES + 255) / 256, 256, 0, stream>>>(dst, cnt);
    dinv_kernel<<<(N_NODES + 255) / 256, 256, 0, stream>>>(cnt, dinv);
    scan1_kernel<<<SCAN_NBLK, 256, 0, stream>>>(cnt, rowp, blks);
    scan2_kernel<<<1, 128, 0, stream>>>(blks, SCAN_NBLK);
    scan3_kernel<<<SCAN_NBLK, 256, 0, stream>>>(rowp, blks, fill);
    wpack_kernel<<<(N_CONVS * 16384 + 255) / 256, 256, 0, stream>>>(conv_w, W2g);

    // --- fused: CSR fill scatter || GEMM layer 0 (fp16 H0 out) ---
    fill_gemm0_kernel<<<FILL_BLOCKS + GEMM64_BLOCKS, 256, 0, stream>>>(
        src, dst, dinv, fill, edges, x_in, conv_w, (uint2*)bufHa);

    // --- layers 0..2: fused agg_L + GEMM_{L+1} (fp16 H_{L+1} out) ---
    __half* hin = bufHa;
    __half* hout = bufHb;
    for (int L = 0; L < N_CONVS - 1; L++) {
        aggfuse_kernel<<<FUSE_BLOCKS, 256, 0, stream>>>(
            (const uint4*)hin, rowp, edges, dinv,
            (const float4*)(conv_b + (size_t)L * F),
            W2g + (size_t)(L + 1) * W2_LAYER, hout);
        __half* tmp = hin; hin = hout; hout = tmp;
    }

    // --- final layer: plain agg (fp32 out for pooling) ---
    agg_kernel<<<(N_NODES + 3) / 4, 256, 0, stream>>>(
        (const uint4*)hin, rowp, edges, dinv,
        (const float4*)(conv_b + (size_t)(N_CONVS - 1) * F), (float4*)bufA);

    // --- mean-pool + FC head ---
    pool_fc_kernel<<<N_GRAPHS, 256, 0, stream>>>(bufA, batch, fc1w, fc1b, fc2w, fc2b, out);
}

// Round 11
// 635.589 us; speedup vs baseline: 1.0981x; 1.0981x over previous
//
#include <hip/hip_runtime.h>
#include <hip/hip_fp16.h>

#define N_NODES 100000
#define N_EDGES 1600000
#define N_GRAPHS 512
#define F 128
#define N_CONVS 4
#define SCAN_NBLK ((N_NODES + 1023) / 1024)   // 98
#define FILL_BLOCKS ((N_EDGES + 255) / 256)   // 6250
#define NWIN 8
#define WIN_SZ ((N_NODES + NWIN - 1) / NWIN)  // 12500 dst-nodes per window

// packed W2 row stride: 256 bf16 (hi/lo interleaved) padded to 264 = 132 dwords
#define W2_STRIDE 132
#define W2_LAYER (128 * W2_STRIDE)            // dwords per layer

typedef __attribute__((ext_vector_type(8))) short short8;   // 8 bf16 (4 VGPRs)
typedef __attribute__((ext_vector_type(4))) float f32x4;

union FragU { uint4 u; short8 v; };
union HU4 { uint4 u; __half2 h[4]; };

__device__ __forceinline__ float4 fma4(float w, float4 v, float4 a) {
    a.x = fmaf(w, v.x, a.x); a.y = fmaf(w, v.y, a.y);
    a.z = fmaf(w, v.z, a.z); a.w = fmaf(w, v.w, a.w);
    return a;
}

// split f into truncated-bf16 hi/lo, packed (hi in low16, lo in high16).
__device__ __forceinline__ unsigned int pack_hilo(float f) {
    unsigned int u = __float_as_uint(f);
    unsigned int hb = u & 0xFFFF0000u;
    float d = f - __uint_as_float(hb);
    unsigned int lb = __float_as_uint(d) >> 16;
    return (u >> 16) | (lb << 16);
}

// ---------------- CSR build ----------------

__global__ void count_kernel(const int* __restrict__ dst, int* __restrict__ cnt) {
    int e = blockIdx.x * blockDim.x + threadIdx.x;
    if (e < N_EDGES) atomicAdd(&cnt[dst[e]], 1);
}

__global__ void dinv_kernel(const int* __restrict__ cnt, float* __restrict__ dinv) {
    int n = blockIdx.x * blockDim.x + threadIdx.x;
    if (n < N_NODES) dinv[n] = rsqrtf((float)cnt[n] + 2.0f);  // improved=True
}

__global__ void scan1_kernel(const int* __restrict__ cnt, int* __restrict__ excl,
                             int* __restrict__ blksum) {
    __shared__ int sums[256];
    int t = threadIdx.x;
    int base = blockIdx.x * 1024 + t * 4;
    int v0 = 0, v1 = 0, v2 = 0, v3 = 0;
    if (base + 0 < N_NODES) v0 = cnt[base + 0];
    if (base + 1 < N_NODES) v1 = cnt[base + 1];
    if (base + 2 < N_NODES) v2 = cnt[base + 2];
    if (base + 3 < N_NODES) v3 = cnt[base + 3];
    int s = v0 + v1 + v2 + v3;
    sums[t] = s;
    __syncthreads();
    for (int off = 1; off < 256; off <<= 1) {
        int y = (t >= off) ? sums[t - off] : 0;
        __syncthreads();
        sums[t] += y;
        __syncthreads();
    }
    int pre = sums[t] - s;
    if (base + 0 < N_NODES) excl[base + 0] = pre;
    if (base + 1 < N_NODES) excl[base + 1] = pre + v0;
    if (base + 2 < N_NODES) excl[base + 2] = pre + v0 + v1;
    if (base + 3 < N_NODES) excl[base + 3] = pre + v0 + v1 + v2;
    if (t == 255) blksum[blockIdx.x] = sums[255];
}

__global__ void scan2_kernel(int* __restrict__ blksum, int nblk) {
    __shared__ int sh[128];
    int t = threadIdx.x;
    int v = (t < nblk) ? blksum[t] : 0;
    sh[t] = v;
    __syncthreads();
    for (int off = 1; off < 128; off <<= 1) {
        int y = (t >= off) ? sh[t - off] : 0;
        __syncthreads();
        sh[t] += y;
        __syncthreads();
    }
    if (t < nblk) blksum[t] = sh[t] - v;
}

__global__ void scan3_kernel(int* __restrict__ rowptr, const int* __restrict__ blksum,
                             int* __restrict__ fill) {
    int t = threadIdx.x;
    int base = blockIdx.x * 1024 + t * 4;
    int off = blksum[blockIdx.x];
#pragma unroll
    for (int i = 0; i < 4; i++) {
        int idx = base + i;
        if (idx < N_NODES) {
            int v = rowptr[idx] + off;
            rowptr[idx] = v;
            fill[idx] = v;
        }
    }
    if (blockIdx.x == 0 && t == 0) rowptr[N_NODES] = N_EDGES;
}

// ---------------- XCD-pinned windowed CSR fill ----------------
// Write amplification killer: edges[] lines were each written by ~all 8 XCDs
// (1 merge/XCD -> 8x64 B write-back per line, ~102 MB measured). Partition dst
// into 8 windows; block b handles window b&7 over edge-chunk b>>3. With the
// round-robin blockIdx%8 -> XCD mapping, each window's contiguous edges region
// (~1.6 MB < 4 MB L2) is written by ONE XCD -> full line merging. Cost: 8x
// streaming re-read of src/dst (~102 MB at HBM rate).

__global__ __launch_bounds__(256) void fillw_kernel(
        const int* __restrict__ src, const int* __restrict__ dst,
        const float* __restrict__ dinv, int* __restrict__ fill,
        int2* __restrict__ edges) {
    int b = blockIdx.x;
    int w = b & (NWIN - 1);
    int e = (b >> 3) * 256 + threadIdx.x;
    if (e < N_EDGES) {
        int d = dst[e];
        if (d / WIN_SZ == w) {
            int s = src[e];
            int pos = atomicAdd(&fill[d], 1);
            edges[pos] = make_int2(s, __float_as_int(dinv[s] * dinv[d]));
        }
    }
}

// ---------------- W pre-pack: conv_w[L][k][n] -> W2g[L][n][132 dwords] ----------------

__global__ void wpack_kernel(const float* __restrict__ conv_w, unsigned int* __restrict__ W2g) {
    int idx = blockIdx.x * 256 + threadIdx.x;
    if (idx < N_CONVS * 16384) {
        int L = idx >> 14;
        int e = idx & 16383;
        int k = e >> 7;
        int n = e & 127;
        float f = conv_w[(size_t)L * 16384 + k * 128 + n];
        W2g[(size_t)L * W2_LAYER + n * W2_STRIDE + k] = pack_hilo(f);
    }
}

// ---------------- MFMA GEMM: H = X @ W via split-bf16, 32 rows/wave, fp16 out ------

__global__ __launch_bounds__(256, 2) void gemm_mfma_kernel(const float* __restrict__ X,
                                                           const unsigned int* __restrict__ W2g,
                                                           __half* __restrict__ Hh) {
    __shared__ unsigned int wlds[128 * W2_STRIDE];   // 67584 B
    int t = threadIdx.x;

    {   // stage packed W (16896 dwords)
        const uint4* s4 = (const uint4*)W2g;
        uint4* d4 = (uint4*)wlds;
#pragma unroll
        for (int i = 0; i < 17; i++) {
            int idx = i * 256 + t;
            if (idx < (128 * W2_STRIDE) / 4) d4[idx] = s4[idx];
        }
    }
    __syncthreads();

    int w = t >> 6;
    int l = t & 63;
    int m = l & 15;        // A row within tile / B col / C col
    int q = l >> 4;        // quad: k-offset q*8, C row-offset q*4
    int r0 = blockIdx.x * 128 + w * 32 + m;
    int r1 = r0 + 16;
    int r0c = (r0 > N_NODES - 1) ? (N_NODES - 1) : r0;
    int r1c = (r1 > N_NODES - 1) ? (N_NODES - 1) : r1;
    const float4* X4 = (const float4*)X;

    uint4 a0[8], a1[8];
#pragma unroll
    for (int i = 0; i < 8; i++) {
        float4 xv = X4[(size_t)r0c * 32 + i * 4 + q];
        a0[i].x = pack_hilo(xv.x); a0[i].y = pack_hilo(xv.y);
        a0[i].z = pack_hilo(xv.z); a0[i].w = pack_hilo(xv.w);
        float4 yv = X4[(size_t)r1c * 32 + i * 4 + q];
        a1[i].x = pack_hilo(yv.x); a1[i].y = pack_hilo(yv.y);
        a1[i].z = pack_hilo(yv.z); a1[i].w = pack_hilo(yv.w);
    }

    f32x4 acc0[8], acc1[8];
#pragma unroll
    for (int nb = 0; nb < 8; nb++) {
        acc0[nb] = (f32x4){0.f, 0.f, 0.f, 0.f};
        acc1[nb] = (f32x4){0.f, 0.f, 0.f, 0.f};
    }

#pragma unroll
    for (int nb = 0; nb < 8; nb++) {
        const unsigned int* wb = &wlds[(nb * 16 + m) * W2_STRIDE];
#pragma unroll
        for (int i = 0; i < 8; i++) {
            uint4 b = *(const uint4*)(wb + i * 16 + q * 4);
            FragU fa0, fa1, fb, fr;
            fa0.u = a0[i]; fa1.u = a1[i]; fb.u = b;
            acc0[nb] = __builtin_amdgcn_mfma_f32_16x16x32_bf16(fa0.v, fb.v, acc0[nb], 0, 0, 0);
            acc1[nb] = __builtin_amdgcn_mfma_f32_16x16x32_bf16(fa1.v, fb.v, acc1[nb], 0, 0, 0);
            fr.u.x = (b.x >> 16) | (b.x << 16);
            fr.u.y = (b.y >> 16) | (b.y << 16);
            fr.u.z = (b.z >> 16) | (b.z << 16);
            fr.u.w = (b.w >> 16) | (b.w << 16);
            acc0[nb] = __builtin_amdgcn_mfma_f32_16x16x32_bf16(fa0.v, fr.v, acc0[nb], 0, 0, 0);
            acc1[nb] = __builtin_amdgcn_mfma_f32_16x16x32_bf16(fa1.v, fr.v, acc1[nb], 0, 0, 0);
        }
    }

    // C/D: col = m, row = q*4 + r within tile
    int rbase = blockIdx.x * 128 + w * 32 + q * 4;
#pragma unroll
    for (int nb = 0; nb < 8; nb++) {
#pragma unroll
        for (int r = 0; r < 4; r++) {
            int row = rbase + r;
            if (row < N_NODES) Hh[(size_t)row * F + nb * 16 + m] = __float2half(acc0[nb][r]);
            int row1 = row + 16;
            if (row1 < N_NODES) Hh[(size_t)row1 * F + nb * 16 + m] = __float2half(acc1[nb][r]);
        }
    }
}

// ---------------- Aggregation: x_out = relu(agg + 2*dinv^2*h + b), fp16 H ----------
// One wave per node; lane = (slot = lane>>4, c16 = lane&15); uint4 gathers
// (8 fp16 channels/lane, 16 lane-requests per H-row, 4 edges per instruction).

__global__ __launch_bounds__(256) void agg_kernel(const uint4* __restrict__ H16,
                                                  const int* __restrict__ rowptr,
                                                  const int2* __restrict__ edges,
                                                  const float* __restrict__ dinv,
                                                  const float4* __restrict__ bias4,
                                                  float4* __restrict__ Xo4) {
    int node = blockIdx.x * 4 + (threadIdx.x >> 6);
    if (node >= N_NODES) return;
    int lane = threadIdx.x & 63;
    int c16 = lane & 15;
    int slot = lane >> 4;

    int lo = rowptr[node];
    int hi = rowptr[node + 1];
    int him1 = hi - 1;

    float4 aL = make_float4(0.f, 0.f, 0.f, 0.f);
    float4 aH = make_float4(0.f, 0.f, 0.f, 0.f);

    for (int i = lo + slot; i < hi; i += 16) {
        int s[4]; float w[4]; uint4 v[4];
#pragma unroll
        for (int j = 0; j < 4; j++) {
            int ij = i + 4 * j;
            int cj = (ij < him1) ? ij : him1;
            int2 e = edges[cj];
            s[j] = e.x;
            w[j] = (ij < hi) ? __int_as_float(e.y) : 0.f;
        }
#pragma unroll
        for (int j = 0; j < 4; j++) v[j] = H16[(size_t)s[j] * 16 + c16];
#pragma unroll
        for (int j = 0; j < 4; j++) {
            HU4 x; x.u = v[j];
            float2 p0 = __half22float2(x.h[0]);
            float2 p1 = __half22float2(x.h[1]);
            float2 p2 = __half22float2(x.h[2]);
            float2 p3 = __half22float2(x.h[3]);
            aL.x = fmaf(w[j], p0.x, aL.x); aL.y = fmaf(w[j], p0.y, aL.y);
            aL.z = fmaf(w[j], p1.x, aL.z); aL.w = fmaf(w[j], p1.y, aL.w);
            aH.x = fmaf(w[j], p2.x, aH.x); aH.y = fmaf(w[j], p2.y, aH.y);
            aH.z = fmaf(w[j], p3.x, aH.z); aH.w = fmaf(w[j], p3.y, aH.w);
        }
    }

    aL.x += __shfl_down(aL.x, 32, 64); aL.y += __shfl_down(aL.y, 32, 64);
    aL.z += __shfl_down(aL.z, 32, 64); aL.w += __shfl_down(aL.w, 32, 64);
    aH.x += __shfl_down(aH.x, 32, 64); aH.y += __shfl_down(aH.y, 32, 64);
    aH.z += __shfl_down(aH.z, 32, 64); aH.w += __shfl_down(aH.w, 32, 64);
    aL.x += __shfl_down(aL.x, 16, 64); aL.y += __shfl_down(aL.y, 16, 64);
    aL.z += __shfl_down(aL.z, 16, 64); aL.w += __shfl_down(aL.w, 16, 64);
    aH.x += __shfl_down(aH.x, 16, 64); aH.y += __shfl_down(aH.y, 16, 64);
    aH.z += __shfl_down(aH.z, 16, 64); aH.w += __shfl_down(aH.w, 16, 64);

    if (slot == 0) {
        float dn = dinv[node];
        float sw = 2.0f * dn * dn;
        HU4 x; x.u = H16[(size_t)node * 16 + c16];
        float2 p0 = __half22float2(x.h[0]);
        float2 p1 = __half22float2(x.h[1]);
        float2 p2 = __half22float2(x.h[2]);
        float2 p3 = __half22float2(x.h[3]);
        float4 bL = bias4[c16 * 2];
        float4 bH = bias4[c16 * 2 + 1];
        float4 rL, rH;
        rL.x = fmaxf(fmaf(sw, p0.x, aL.x) + bL.x, 0.f);
        rL.y = fmaxf(fmaf(sw, p0.y, aL.y) + bL.y, 0.f);
        rL.z = fmaxf(fmaf(sw, p1.x, aL.z) + bL.z, 0.f);
        rL.w = fmaxf(fmaf(sw, p1.y, aL.w) + bL.w, 0.f);
        rH.x = fmaxf(fmaf(sw, p2.x, aH.x) + bH.x, 0.f);
        rH.y = fmaxf(fmaf(sw, p2.y, aH.y) + bH.y, 0.f);
        rH.z = fmaxf(fmaf(sw, p3.x, aH.z) + bH.z, 0.f);
        rH.w = fmaxf(fmaf(sw, p3.y, aH.w) + bH.w, 0.f);
        Xo4[(size_t)node * 32 + c16 * 2]     = rL;
        Xo4[(size_t)node * 32 + c16 * 2 + 1] = rH;
    }
}

// ---------------- Fused mean-pool + FC1(relu) + FC2 ----------------

__global__ __launch_bounds__(256) void pool_fc_kernel(const float* __restrict__ x,
                                                      const int* __restrict__ batch,
                                                      const float* __restrict__ fc1w,
                                                      const float* __restrict__ fc1b,
                                                      const float* __restrict__ fc2w,
                                                      const float* __restrict__ fc2b,
                                                      float* __restrict__ out) {
    __shared__ float part[2][F];
    __shared__ float pooled[F];
    __shared__ int bnd[2];
    __shared__ float red[2];
    int g = blockIdx.x, t = threadIdx.x;
    int c = t & 127, hlf = t >> 7;

    if (t < 2) {
        int target = g + t;
        int lo = 0, hi = N_NODES;
        while (lo < hi) {
            int m = (lo + hi) >> 1;
            if (batch[m] < target) lo = m + 1;
            else hi = m;
        }
        bnd[t] = lo;
    }
    __syncthreads();
    int lo = bnd[0], hi = bnd[1];

    float s = 0.f;
    int n = lo + hlf;
    for (; n + 6 < hi; n += 8) {
        float v0 = x[(size_t)n * F + c];
        float v1 = x[(size_t)(n + 2) * F + c];
        float v2 = x[(size_t)(n + 4) * F + c];
        float v3 = x[(size_t)(n + 6) * F + c];
        s += (v0 + v1) + (v2 + v3);
    }
    for (; n < hi; n += 2) s += x[(size_t)n * F + c];
    part[hlf][c] = s;
    __syncthreads();

    if (t < F) {
        float cntf = fmaxf((float)(hi - lo), 1.0f);
        pooled[c] = (part[0][c] + part[1][c]) / cntf;
    }
    __syncthreads();

    if (t < F) {
        float acc = fc1b[t];
#pragma unroll 4
        for (int k = 0; k < F; k++) acc = fmaf(pooled[k], fc1w[k * F + t], acc);
        acc = fmaxf(acc, 0.f);

        float p = acc * fc2w[t];
#pragma unroll
        for (int o = 32; o > 0; o >>= 1) p += __shfl_down(p, o, 64);
        if ((t & 63) == 0) red[t >> 6] = p;
    }
    __syncthreads();
    if (t == 0) out[g] = red[0] + red[1] + fc2b[0];
}

// ---------------- launch ----------------

extern "C" void kernel_launch(void* const* d_in, const int* in_sizes, int n_in,
                              void* d_out, int out_size, void* d_ws, size_t ws_size,
                              hipStream_t stream) {
    const float* x_in   = (const float*)d_in[0];
    const int*   eidx   = (const int*)d_in[1];
    const int*   batch  = (const int*)d_in[2];
    const float* conv_w = (const float*)d_in[4];
    const float* conv_b = (const float*)d_in[5];
    const float* fc1w   = (const float*)d_in[6];
    const float* fc1b   = (const float*)d_in[7];
    const float* fc2w   = (const float*)d_in[8];
    const float* fc2b   = (const float*)d_in[9];
    float* out = (float*)d_out;

    const int* src = eidx;
    const int* dst = eidx + N_EDGES;

    char* ws = (char*)d_ws;
    size_t off = 0;
    auto alloc = [&](size_t bytes) -> char* {
        char* p = ws + off;
        off += (bytes + 255) & ~(size_t)255;
        return p;
    };
    float*  bufA  = (float*)alloc((size_t)N_NODES * F * 4);    // 51.2 MB fp32 (agg out)
    __half* bufH  = (__half*)alloc((size_t)N_NODES * F * 2);   // 25.6 MB fp16 (gemm out)
    float*  dinv  = (float*)alloc((size_t)N_NODES * 4);
    int*    cnt   = (int*)alloc((size_t)N_NODES * 4);
    int*    rowp  = (int*)alloc((size_t)(N_NODES + 1) * 4);
    int*    fill  = (int*)alloc((size_t)N_NODES * 4);
    int2*   edges = (int2*)alloc((size_t)N_EDGES * 8);         // 12.8 MB packed
    unsigned int* W2g = (unsigned int*)alloc((size_t)N_CONVS * W2_LAYER * 4);  // 264 KB
    int*    blks  = (int*)alloc(128 * 4);
    (void)ws_size; (void)in_sizes; (void)n_in; (void)out_size;

    // --- CSR prep + W pre-pack ---
    hipMemsetAsync(cnt, 0, (size_t)N_NODES * 4, stream);
    count_kernel<<<(N_EDGES + 255) / 256, 256, 0, stream>>>(dst, cnt);
    dinv_kernel<<<(N_NODES + 255) / 256, 256, 0, stream>>>(cnt, dinv);
    scan1_kernel<<<SCAN_NBLK, 256, 0, stream>>>(cnt, rowp, blks);
    scan2_kernel<<<1, 128, 0, stream>>>(blks, SCAN_NBLK);
    scan3_kernel<<<SCAN_NBLK, 256, 0, stream>>>(rowp, blks, fill);
    wpack_kernel<<<(N_CONVS * 16384 + 255) / 256, 256, 0, stream>>>(conv_w, W2g);

    // --- XCD-pinned windowed CSR fill ---
    fillw_kernel<<<FILL_BLOCKS * NWIN, 256, 0, stream>>>(src, dst, dinv, fill, edges);

    // --- 4 GCN layers: MFMA GEMM (fp16 out) + gather agg (fp32 out) ---
    const float* cur = x_in;
    for (int L = 0; L < N_CONVS; L++) {
        gemm_mfma_kernel<<<(N_NODES + 127) / 128, 256, 0, stream>>>(
            cur, W2g + (size_t)L * W2_LAYER, bufH);
        agg_kernel<<<(N_NODES + 3) / 4, 256, 0, stream>>>(
            (const uint4*)bufH, rowp, edges, dinv,
            (const float4*)(conv_b + (size_t)L * F), (float4*)bufA);
        cur = bufA;
    }

    // --- mean-pool + FC head ---
    pool_fc_kernel<<<N_GRAPHS, 256, 0, stream>>>(bufA, batch, fc1w, fc1b, fc2w, fc2b, out);
}